// Round 2
// baseline (107.094 us; speedup 1.0000x reference)
//
#include <hip/hip_runtime.h>
#include <stdint.h>

// Problem: x0,y0 [B=64, C=36, L=4096] float32.
// out = y0 * (mean(x0, -1) + mean(y0, -1)), float32.
// Memory-bound: 113 MB total traffic -> ~18 us roofline at 6.3 TB/s.

#define LL    4096
#define ROWS  (64 * 36)     // 2304 blocks, one per (b,c) row
#define BLOCK 256           // 4 waves; 1024 float4 per row -> 4 float4/thread

__global__ __launch_bounds__(BLOCK) void spo2_rowscale(
    const float* __restrict__ x,
    const float* __restrict__ y,
    float* __restrict__ out)
{
    const int row = blockIdx.x;
    const size_t base = (size_t)row * LL;
    const int tid = threadIdx.x;

    const float4* xv = (const float4*)(x + base);
    const float4* yv = (const float4*)(y + base);
    float4*       ov = (float4*)(out + base);

    // 4096 floats = 1024 float4 per row; 256 threads -> 4 float4 each
    float4 xr[4], yr[4];
#pragma unroll
    for (int i = 0; i < 4; ++i) {
        xr[i] = xv[tid + i * BLOCK];
        yr[i] = yv[tid + i * BLOCK];
    }

    // per-thread partial of (sum_x + sum_y)
    float s = 0.f;
#pragma unroll
    for (int i = 0; i < 4; ++i) {
        s += xr[i].x + xr[i].y + xr[i].z + xr[i].w;
        s += yr[i].x + yr[i].y + yr[i].z + yr[i].w;
    }

    // wave-64 butterfly reduce
#pragma unroll
    for (int off = 32; off > 0; off >>= 1)
        s += __shfl_down(s, off, 64);

    __shared__ float rs[BLOCK / 64];
    const int wid  = tid >> 6;
    const int lane = tid & 63;
    if (lane == 0) rs[wid] = s;
    __syncthreads();

    float total = 0.f;
#pragma unroll
    for (int w = 0; w < BLOCK / 64; ++w) total += rs[w];
    const float scale = total * (1.0f / (float)LL);

#pragma unroll
    for (int i = 0; i < 4; ++i) {
        float4 o;
        o.x = yr[i].x * scale;
        o.y = yr[i].y * scale;
        o.z = yr[i].z * scale;
        o.w = yr[i].w * scale;
        ov[tid + i * BLOCK] = o;
    }
}

extern "C" void kernel_launch(void* const* d_in, const int* in_sizes, int n_in,
                              void* d_out, int out_size, void* d_ws, size_t ws_size,
                              hipStream_t stream) {
    const float* x = (const float*)d_in[0];
    const float* y = (const float*)d_in[1];
    float* out = (float*)d_out;
    spo2_rowscale<<<ROWS, BLOCK, 0, stream>>>(x, y, out);
}